// Round 7
// baseline (358.049 us; speedup 1.0000x reference)
//
#include <hip/hip_runtime.h>
#include <hip/hip_bf16.h>

#define N_ 100000
#define E_ 1600000
#define D_ 128
#define H_ 4
#define C_ 32

using bf16 = __hip_bfloat16;
typedef __attribute__((ext_vector_type(8))) short short8;
typedef __attribute__((ext_vector_type(4))) float f32x4;

__device__ __forceinline__ float u2f(unsigned u) { return __uint_as_float(u); }
__device__ __forceinline__ unsigned short f2bu(float v) {
  bf16 t = __float2bfloat16(v);
  return *(unsigned short*)&t;
}

// ---------------------------------------------------------------------------
// Kernel 1: h = x @ W^T via MFMA 16x16x32 bf16, fused attention logits.
// (unchanged from round 6 — passed at absmax 0.0625)
// ---------------------------------------------------------------------------
__global__ __launch_bounds__(256) void k_linear_mfma(
    const float* __restrict__ x, const float* __restrict__ W,
    const float* __restrict__ att_src, const float* __restrict__ att_dst,
    bf16* __restrict__ h, float* __restrict__ a_src, float* __restrict__ a_dst) {
  __shared__ unsigned short WB[16384];    // 32 KB, pre-swizzled B fragments
  __shared__ unsigned short XS[64 * 128]; // 16 KB, A staging + epilogue xpose
  __shared__ float ats[128], atd[128];
  const int tid = threadIdx.x;
  const int lane = tid & 63, w = tid >> 6;
  const int n15 = lane & 15, quad = lane >> 4;

  for (int i = tid; i < 16384; i += 256) {
    const int n = i >> 7, k = i & 127;
    const int kk = k >> 5, q = (k >> 3) & 3, j = k & 7;
    const int frag = kk * 8 + (n >> 4);
    WB[frag * 512 + q * 128 + (n & 15) * 8 + j] = f2bu(W[n * 128 + k]);
  }
  if (tid < 128) { ats[tid] = att_src[tid]; atd[tid] = att_dst[tid]; }

  const int nrb = (N_ + 63) / 64;  // 1563
  for (int rb = blockIdx.x; rb < nrb; rb += gridDim.x) {
    const int row0 = rb * 64;
    __syncthreads();
    for (int idx = tid; idx < 2048; idx += 256) {
      const int r = idx >> 5;
      const int c = (idx & 31) * 4;
      float4 xv = make_float4(0.f, 0.f, 0.f, 0.f);
      if (row0 + r < N_) xv = *(const float4*)&x[(size_t)(row0 + r) * 128 + c];
      ushort4 o;
      o.x = f2bu(xv.x); o.y = f2bu(xv.y); o.z = f2bu(xv.z); o.w = f2bu(xv.w);
      *(ushort4*)&XS[r * 128 + c] = o;
    }
    __syncthreads();

    f32x4 acc[8] = {};
    const int arow = w * 16 + n15;
#pragma unroll
    for (int kk = 0; kk < 4; kk++) {
      const short8 a = *(const short8*)&XS[arow * 128 + kk * 32 + quad * 8];
#pragma unroll
      for (int t = 0; t < 8; t++) {
        const short8 b = *(const short8*)&WB[(kk * 8 + t) * 512 + lane * 8];
        acc[t] = __builtin_amdgcn_mfma_f32_16x16x32_bf16(a, b, acc[t], 0, 0, 0);
      }
    }

    __syncthreads();
#pragma unroll
    for (int t = 0; t < 8; t++)
#pragma unroll
      for (int reg = 0; reg < 4; reg++)
        XS[(w * 16 + quad * 4 + reg) * 128 + t * 16 + n15] =
            f2bu(acc[t][reg]);
    __syncthreads();
    {
      const int row = tid >> 2;
      const int hd = tid & 3;
      const int cb = hd * 32;
      const int grow = row0 + row;
      float ps = 0.f, pd = 0.f;
      if (grow < N_) {
#pragma unroll
        for (int g = 0; g < 4; g++) {
          const uint4 v = *(const uint4*)&XS[row * 128 + cb + g * 8];
          *(uint4*)&h[(size_t)grow * 128 + cb + g * 8] = v;
          const unsigned uu[4] = {v.x, v.y, v.z, v.w};
#pragma unroll
          for (int p = 0; p < 4; p++) {
            const float f0 = u2f(uu[p] << 16);
            const float f1 = u2f(uu[p] & 0xffff0000u);
            const int cc = cb + g * 8 + p * 2;
            ps = fmaf(f0, ats[cc], ps);     ps = fmaf(f1, ats[cc + 1], ps);
            pd = fmaf(f0, atd[cc], pd);     pd = fmaf(f1, atd[cc + 1], pd);
          }
        }
        a_src[grow * 4 + hd] = ps;
        a_dst[grow * 4 + hd] = pd;
      }
    }
  }
}

// ---------------------------------------------------------------------------
// Kernel 2: 8-chain linked-list build. nxt2[e] = (src, prev) packed int2,
// written coalesced; atomicExch hits the 3.2 MB head table.
// ---------------------------------------------------------------------------
__global__ __launch_bounds__(256) void k_link(const int* __restrict__ ei,
                                              int* __restrict__ head8,
                                              int2* __restrict__ nxt2) {
  const int e = blockIdx.x * 256 + threadIdx.x;
  if (e >= E_) return;
  const int d = ei[E_ + e];
  const int prev = atomicExch(&head8[d * 8 + (e & 7)], e);
  nxt2[e] = make_int2(ei[e], prev);
}

// ---------------------------------------------------------------------------
// Kernel 3: gather, 8 chains/node. One wave per node.
// lane = j*8+cg: chain j (0..7), channels [cg*16, cg*16+16), head = cg>>1.
// Per hop: each lane advances its chain one edge — weight computed once in
// the right lane (no shuffles in the hop), h read as 2x b128.
// End: shfl_xor 8/16/32 reduces chains; fused bias+|.|+LN+GELU; lanes 0..7
// store. mag: cos^2+sin^2==1 to 1ulp -> sqrt(v^2+1e-12) (err ~5e-6 << thr).
// ---------------------------------------------------------------------------
__global__ __launch_bounds__(256) void k_gather8(
    const int* __restrict__ head8, const int2* __restrict__ nxt2,
    const float* __restrict__ a_src, const float* __restrict__ a_dst,
    const bf16* __restrict__ h, const float* __restrict__ bias,
    const float* __restrict__ gamma, const float* __restrict__ beta,
    float* __restrict__ out) {
  const int lane = threadIdx.x & 63;
  const int d = blockIdx.x * 4 + (threadIdx.x >> 6);
  if (d >= N_) return;
  const int j = lane >> 3;    // chain
  const int cg = lane & 7;    // channel group (16 ch)
  const int head = cg >> 1;
  const float ad = a_dst[d * 4 + head];

  int e = head8[d * 8 + j];
  float acc[16];
#pragma unroll
  for (int k = 0; k < 16; k++) acc[k] = 0.f;
  float sumw = 0.f;

  while (__any(e != -1)) {
    const int c = (e < 0) ? 0 : e;
    const int2 sn = nxt2[c];          // (src, next)
    const int s = sn.x;
    const uint4 u0 = *(const uint4*)&h[(size_t)s * 128 + cg * 16];
    const uint4 u1 = *(const uint4*)&h[(size_t)s * 128 + cg * 16 + 8];
    float ev = a_src[s * 4 + head] + ad;
    ev = (ev > 0.f) ? ev : 0.2f * ev;
    const float w = (e < 0) ? 0.f : __expf(ev);
    const unsigned uu[8] = {u0.x, u0.y, u0.z, u0.w, u1.x, u1.y, u1.z, u1.w};
#pragma unroll
    for (int p = 0; p < 8; p++) {
      acc[p * 2]     = fmaf(w, u2f(uu[p] << 16), acc[p * 2]);
      acc[p * 2 + 1] = fmaf(w, u2f(uu[p] & 0xffff0000u), acc[p * 2 + 1]);
    }
    sumw += w;
    e = (e < 0) ? -1 : sn.y;
  }

  // reduce across the 8 chains (lane bits 3..5)
#pragma unroll
  for (int off = 8; off <= 32; off <<= 1) {
#pragma unroll
    for (int k = 0; k < 16; k++) acc[k] += __shfl_xor(acc[k], off);
    sumw += __shfl_xor(sumw, off);
  }

  const float inv = 1.0f / (sumw + 1e-16f);
  float biv[16], gav[16], bev[16];
#pragma unroll
  for (int g = 0; g < 4; g++) {
    *(float4*)&biv[g * 4] = *(const float4*)&bias[cg * 16 + g * 4];
    *(float4*)&gav[g * 4] = *(const float4*)&gamma[cg * 16 + g * 4];
    *(float4*)&bev[g * 4] = *(const float4*)&beta[cg * 16 + g * 4];
  }

  float m[16], part = 0.f;
#pragma unroll
  for (int k = 0; k < 16; k++) {
    const float v = acc[k] * inv + biv[k];
    m[k] = sqrtf(v * v + 1e-12f);
    part += m[k];
  }
#pragma unroll
  for (int off = 1; off <= 4; off <<= 1) part += __shfl_xor(part, off);
  const float mu = part * (1.0f / 128.0f);
  float q = 0.f;
#pragma unroll
  for (int k = 0; k < 16; k++) {
    m[k] -= mu;
    q += m[k] * m[k];
  }
#pragma unroll
  for (int off = 1; off <= 4; off <<= 1) q += __shfl_xor(q, off);
  const float rstd = rsqrtf(q * (1.0f / 128.0f) + 1e-5f);

  float o[16];
#pragma unroll
  for (int k = 0; k < 16; k++) {
    const float hn = m[k] * rstd * gav[k] + bev[k];
    o[k] = 0.5f * hn * (1.0f + erff(hn * 0.70710678118654752f));
  }
  if (lane < 8) {
#pragma unroll
    for (int g = 0; g < 4; g++)
      *(float4*)&out[(size_t)d * 128 + cg * 16 + g * 4] = *(float4*)&o[g * 4];
  }
}

// ---------------------------------------------------------------------------
extern "C" void kernel_launch(void* const* d_in, const int* in_sizes, int n_in,
                              void* d_out, int out_size, void* d_ws, size_t ws_size,
                              hipStream_t stream) {
  const float* x       = (const float*)d_in[0];
  const int*   ei      = (const int*)d_in[1];
  const float* W       = (const float*)d_in[2];
  const float* att_src = (const float*)d_in[3];
  const float* att_dst = (const float*)d_in[4];
  const float* bias    = (const float*)d_in[5];
  const float* gamma   = (const float*)d_in[7];
  const float* beta    = (const float*)d_in[8];
  float* out = (float*)d_out;

  // workspace (44.8 MB)
  bf16*  h     = (bf16*)d_ws;                        // N*128 bf16 (25.6 MB)
  float* a_src = (float*)(h + (size_t)N_ * D_);      // N*4 f32 (1.6 MB)
  float* a_dst = a_src + (size_t)N_ * H_;            // N*4 f32 (1.6 MB)
  int*   head8 = (int*)(a_dst + (size_t)N_ * H_);    // N*8 int (3.2 MB)
  int2*  nxt2  = (int2*)(head8 + (size_t)N_ * 8);    // E int2 (12.8 MB)

  hipMemsetAsync(head8, 0xFF, (size_t)N_ * 8 * sizeof(int), stream);

  k_linear_mfma<<<768, 256, 0, stream>>>(x, W, att_src, att_dst, h, a_src,
                                         a_dst);
  k_link<<<(E_ + 255) / 256, 256, 0, stream>>>(ei, head8, nxt2);
  k_gather8<<<(N_ + 3) / 4, 256, 0, stream>>>(head8, nxt2, a_src, a_dst, h,
                                              bias, gamma, beta, out);
}

// Round 8
// 340.612 us; speedup vs baseline: 1.0512x; 1.0512x over previous
//
#include <hip/hip_runtime.h>
#include <hip/hip_bf16.h>

#define N_ 100000
#define E_ 1600000
#define D_ 128
#define H_ 4
#define C_ 32

using bf16 = __hip_bfloat16;
typedef __attribute__((ext_vector_type(8))) short short8;
typedef __attribute__((ext_vector_type(4))) float f32x4;

__device__ __forceinline__ float u2f(unsigned u) { return __uint_as_float(u); }
__device__ __forceinline__ unsigned short f2bu(float v) {
  bf16 t = __float2bfloat16(v);
  return *(unsigned short*)&t;
}

// ---------------------------------------------------------------------------
// Kernel 1: h = x @ W^T via MFMA 16x16x32 bf16, fused attention logits.
// (unchanged — known-good since round 6)
// ---------------------------------------------------------------------------
__global__ __launch_bounds__(256) void k_linear_mfma(
    const float* __restrict__ x, const float* __restrict__ W,
    const float* __restrict__ att_src, const float* __restrict__ att_dst,
    bf16* __restrict__ h, float* __restrict__ a_src, float* __restrict__ a_dst) {
  __shared__ unsigned short WB[16384];    // 32 KB, pre-swizzled B fragments
  __shared__ unsigned short XS[64 * 128]; // 16 KB, A staging + epilogue xpose
  __shared__ float ats[128], atd[128];
  const int tid = threadIdx.x;
  const int lane = tid & 63, w = tid >> 6;
  const int n15 = lane & 15, quad = lane >> 4;

  for (int i = tid; i < 16384; i += 256) {
    const int n = i >> 7, k = i & 127;
    const int kk = k >> 5, q = (k >> 3) & 3, j = k & 7;
    const int frag = kk * 8 + (n >> 4);
    WB[frag * 512 + q * 128 + (n & 15) * 8 + j] = f2bu(W[n * 128 + k]);
  }
  if (tid < 128) { ats[tid] = att_src[tid]; atd[tid] = att_dst[tid]; }

  const int nrb = (N_ + 63) / 64;  // 1563
  for (int rb = blockIdx.x; rb < nrb; rb += gridDim.x) {
    const int row0 = rb * 64;
    __syncthreads();
    for (int idx = tid; idx < 2048; idx += 256) {
      const int r = idx >> 5;
      const int c = (idx & 31) * 4;
      float4 xv = make_float4(0.f, 0.f, 0.f, 0.f);
      if (row0 + r < N_) xv = *(const float4*)&x[(size_t)(row0 + r) * 128 + c];
      ushort4 o;
      o.x = f2bu(xv.x); o.y = f2bu(xv.y); o.z = f2bu(xv.z); o.w = f2bu(xv.w);
      *(ushort4*)&XS[r * 128 + c] = o;
    }
    __syncthreads();

    f32x4 acc[8] = {};
    const int arow = w * 16 + n15;
#pragma unroll
    for (int kk = 0; kk < 4; kk++) {
      const short8 a = *(const short8*)&XS[arow * 128 + kk * 32 + quad * 8];
#pragma unroll
      for (int t = 0; t < 8; t++) {
        const short8 b = *(const short8*)&WB[(kk * 8 + t) * 512 + lane * 8];
        acc[t] = __builtin_amdgcn_mfma_f32_16x16x32_bf16(a, b, acc[t], 0, 0, 0);
      }
    }

    __syncthreads();
#pragma unroll
    for (int t = 0; t < 8; t++)
#pragma unroll
      for (int reg = 0; reg < 4; reg++)
        XS[(w * 16 + quad * 4 + reg) * 128 + t * 16 + n15] =
            f2bu(acc[t][reg]);
    __syncthreads();
    {
      const int row = tid >> 2;
      const int hd = tid & 3;
      const int cb = hd * 32;
      const int grow = row0 + row;
      float ps = 0.f, pd = 0.f;
      if (grow < N_) {
#pragma unroll
        for (int g = 0; g < 4; g++) {
          const uint4 v = *(const uint4*)&XS[row * 128 + cb + g * 8];
          *(uint4*)&h[(size_t)grow * 128 + cb + g * 8] = v;
          const unsigned uu[4] = {v.x, v.y, v.z, v.w};
#pragma unroll
          for (int p = 0; p < 4; p++) {
            const float f0 = u2f(uu[p] << 16);
            const float f1 = u2f(uu[p] & 0xffff0000u);
            const int cc = cb + g * 8 + p * 2;
            ps = fmaf(f0, ats[cc], ps);     ps = fmaf(f1, ats[cc + 1], ps);
            pd = fmaf(f0, atd[cc], pd);     pd = fmaf(f1, atd[cc + 1], pd);
          }
        }
        a_src[grow * 4 + hd] = ps;
        a_dst[grow * 4 + hd] = pd;
      }
    }
  }
}

// ---------------------------------------------------------------------------
// Kernel 2: 4-chain linked-list build, packed nxt2[e] = (src, prev).
// nxt2 write coalesced; atomicExch hits the 1.6 MB head table.
// ---------------------------------------------------------------------------
__global__ __launch_bounds__(256) void k_link(const int* __restrict__ ei,
                                              int* __restrict__ head4,
                                              int2* __restrict__ nxt2) {
  const int e = blockIdx.x * 256 + threadIdx.x;
  if (e >= E_) return;
  const int d = ei[E_ + e];
  const int prev = atomicExch(&head4[d * 4 + (e & 3)], e);
  nxt2[e] = make_int2(ei[e], prev);
}

// ---------------------------------------------------------------------------
// Kernel 3: gather, 4 chains/node, one wave per node; lane owns 2 channels.
// Each lane advances ONLY chain (lane&3): one nxt2 8B load (same addr
// across 16 lanes -> HW broadcast), one a_src load, ONE exp for
// (chain lane&3, head lane>>4) — the 16 distinct weights land in the right
// lanes with zero redundancy. Broadcast w/rowoff to FMA lanes via shfl
// from lane (lane&48)|j. Per-lane sumw reduced once at the end.
// ---------------------------------------------------------------------------
__global__ __launch_bounds__(256) void k_gather4(
    const int* __restrict__ head4, const int2* __restrict__ nxt2,
    const float* __restrict__ a_src, const float* __restrict__ a_dst,
    const bf16* __restrict__ h, const float* __restrict__ bias,
    const float* __restrict__ gamma, const float* __restrict__ beta,
    float* __restrict__ out) {
  const int lane = threadIdx.x & 63;
  const int d = blockIdx.x * 4 + (threadIdx.x >> 6);
  if (d >= N_) return;
  const int head = lane >> 4;
  const int srcsel = lane & 48;  // head*16
  const float ad = a_dst[d * 4 + head];
  const int ch = lane * 2;

  int e = head4[d * 4 + (lane & 3)];  // my chain
  float acc0 = 0.f, acc1 = 0.f, sumw_mine = 0.f;

  while (__any(e != -1)) {
    const int c = (e < 0) ? 0 : e;
    const int2 sn = nxt2[c];                    // (src, next) — one 8B load
    const int s = sn.x;
    float ev = a_src[s * 4 + head] + ad;
    ev = (ev > 0.f) ? ev : 0.2f * ev;
    const float w = (e < 0) ? 0.f : __expf(ev);
    sumw_mine += w;
    const int soff = s << 7;

    // broadcast the 4 chains' (w, soff) and accumulate
#pragma unroll
    for (int j = 0; j < 4; j++) {
      const float wj = __shfl(w, srcsel | j);
      const int oj = __shfl(soff, j);
      const __hip_bfloat162 hv = *(const __hip_bfloat162*)&h[oj + ch];
      acc0 = fmaf(wj, __low2float(hv), acc0);
      acc1 = fmaf(wj, __high2float(hv), acc1);
    }
    e = (e < 0) ? -1 : sn.y;
  }

  // sumw = sum over the 4 chains for my head (chain index lives in bits 0-1)
  float sumw = sumw_mine;
  sumw += __shfl_xor(sumw, 1);
  sumw += __shfl_xor(sumw, 2);

  const float inv = 1.0f / (sumw + 1e-16f);
  const float2 bi = *(const float2*)&bias[ch];
  const float v0 = acc0 * inv + bi.x;
  const float v1 = acc1 * inv + bi.y;
  // cos^2+sin^2 == 1 to 1 ulp -> mag = sqrt(v^2 + 1e-12)
  const float m0i = sqrtf(v0 * v0 + 1e-12f);
  const float m1i = sqrtf(v1 * v1 + 1e-12f);

  float s1 = m0i + m1i;
#pragma unroll
  for (int off = 32; off > 0; off >>= 1) s1 += __shfl_xor(s1, off);
  const float mu = s1 * (1.0f / 128.0f);
  const float d0 = m0i - mu, d1 = m1i - mu;
  float q = d0 * d0 + d1 * d1;
#pragma unroll
  for (int off = 32; off > 0; off >>= 1) q += __shfl_xor(q, off);
  const float rstd = rsqrtf(q * (1.0f / 128.0f) + 1e-5f);
  const float2 ga = *(const float2*)&gamma[ch];
  const float2 be = *(const float2*)&beta[ch];
  const float hn0 = d0 * rstd * ga.x + be.x;
  const float hn1 = d1 * rstd * ga.y + be.y;
  const float g0 = 0.5f * hn0 * (1.0f + erff(hn0 * 0.70710678118654752f));
  const float g1 = 0.5f * hn1 * (1.0f + erff(hn1 * 0.70710678118654752f));
  *(float2*)&out[(size_t)d * 128 + ch] = make_float2(g0, g1);
}

// ---------------------------------------------------------------------------
extern "C" void kernel_launch(void* const* d_in, const int* in_sizes, int n_in,
                              void* d_out, int out_size, void* d_ws, size_t ws_size,
                              hipStream_t stream) {
  const float* x       = (const float*)d_in[0];
  const int*   ei      = (const int*)d_in[1];
  const float* W       = (const float*)d_in[2];
  const float* att_src = (const float*)d_in[3];
  const float* att_dst = (const float*)d_in[4];
  const float* bias    = (const float*)d_in[5];
  const float* gamma   = (const float*)d_in[7];
  const float* beta    = (const float*)d_in[8];
  float* out = (float*)d_out;

  // workspace (43.2 MB)
  bf16*  h     = (bf16*)d_ws;                        // N*128 bf16 (25.6 MB)
  float* a_src = (float*)(h + (size_t)N_ * D_);      // N*4 f32 (1.6 MB)
  float* a_dst = a_src + (size_t)N_ * H_;            // N*4 f32 (1.6 MB)
  int*   head4 = (int*)(a_dst + (size_t)N_ * H_);    // N*4 int (1.6 MB)
  int2*  nxt2  = (int2*)(head4 + (size_t)N_ * 4);    // E int2 (12.8 MB)

  hipMemsetAsync(head4, 0xFF, (size_t)N_ * 4 * sizeof(int), stream);

  k_linear_mfma<<<768, 256, 0, stream>>>(x, W, att_src, att_dst, h, a_src,
                                         a_dst);
  k_link<<<(E_ + 255) / 256, 256, 0, stream>>>(ei, head4, nxt2);
  k_gather4<<<(N_ + 3) / 4, 256, 0, stream>>>(head4, nxt2, a_src, a_dst, h,
                                              bias, gamma, beta, out);
}

// Round 9
// 333.714 us; speedup vs baseline: 1.0729x; 1.0207x over previous
//
#include <hip/hip_runtime.h>
#include <hip/hip_bf16.h>

#define N_ 100000
#define E_ 1600000
#define D_ 128
#define H_ 4
#define C_ 32
#define XSTR 136  // padded LDS row stride (shorts): 272 B = 17*16 B

using bf16 = __hip_bfloat16;
typedef __attribute__((ext_vector_type(8))) short short8;
typedef __attribute__((ext_vector_type(4))) float f32x4;

__device__ __forceinline__ float u2f(unsigned u) { return __uint_as_float(u); }
__device__ __forceinline__ unsigned short f2bu(float v) {
  bf16 t = __float2bfloat16(v);
  return *(unsigned short*)&t;
}

// ---------------------------------------------------------------------------
// Kernel 1 (fused): [A] linked-list build for a grid-stride edge chunk;
// [B] h = x @ W^T via MFMA 16x16x32 bf16 + fused attention logits.
// Phases touch disjoint memory — no barrier between them.
// XS uses stride 136 to kill the 4-way/8-bank conflicts of the stride-128
// epilogue transpose (quad stride 544 shorts = 272 dwords ≡ 16 mod 32).
// ---------------------------------------------------------------------------
__global__ __launch_bounds__(256) void k_linear_link(
    const float* __restrict__ x, const float* __restrict__ W,
    const float* __restrict__ att_src, const float* __restrict__ att_dst,
    const int* __restrict__ ei, int* __restrict__ head4,
    int2* __restrict__ nxt2, bf16* __restrict__ h,
    float* __restrict__ a_src, float* __restrict__ a_dst) {
  __shared__ unsigned short WB[16384];      // 32 KB, pre-swizzled B fragments
  __shared__ unsigned short XS[64 * XSTR];  // 17 KB, A staging + epilogue
  __shared__ float ats[128], atd[128];
  const int tid = threadIdx.x;

  // ---- Phase A: link edges (coalesced nxt2 write; atomics on 1.6 MB table)
  for (int e = blockIdx.x * 256 + tid; e < E_; e += gridDim.x * 256) {
    const int d = ei[E_ + e];
    const int prev = atomicExch(&head4[d * 4 + (e & 3)], e);
    nxt2[e] = make_int2(ei[e], prev);
  }

  // ---- Phase B: MFMA linear
  const int lane = tid & 63, w = tid >> 6;
  const int n15 = lane & 15, quad = lane >> 4;

  for (int i = tid; i < 16384; i += 256) {
    const int n = i >> 7, k = i & 127;
    const int kk = k >> 5, q = (k >> 3) & 3, j = k & 7;
    const int frag = kk * 8 + (n >> 4);
    WB[frag * 512 + q * 128 + (n & 15) * 8 + j] = f2bu(W[n * 128 + k]);
  }
  if (tid < 128) { ats[tid] = att_src[tid]; atd[tid] = att_dst[tid]; }

  const int nrb = (N_ + 63) / 64;  // 1563
  for (int rb = blockIdx.x; rb < nrb; rb += gridDim.x) {
    const int row0 = rb * 64;
    __syncthreads();  // XS reuse guard (covers initial WB/ats fill too)
    for (int idx = tid; idx < 2048; idx += 256) {
      const int r = idx >> 5;
      const int c = (idx & 31) * 4;
      float4 xv = make_float4(0.f, 0.f, 0.f, 0.f);
      if (row0 + r < N_) xv = *(const float4*)&x[(size_t)(row0 + r) * 128 + c];
      ushort4 o;
      o.x = f2bu(xv.x); o.y = f2bu(xv.y); o.z = f2bu(xv.z); o.w = f2bu(xv.w);
      *(ushort4*)&XS[r * XSTR + c] = o;
    }
    __syncthreads();

    f32x4 acc[8] = {};
    const int arow = w * 16 + n15;
#pragma unroll
    for (int kk = 0; kk < 4; kk++) {
      const short8 a = *(const short8*)&XS[arow * XSTR + kk * 32 + quad * 8];
#pragma unroll
      for (int t = 0; t < 8; t++) {
        const short8 b = *(const short8*)&WB[(kk * 8 + t) * 512 + lane * 8];
        acc[t] = __builtin_amdgcn_mfma_f32_16x16x32_bf16(a, b, acc[t], 0, 0, 0);
      }
    }

    __syncthreads();
#pragma unroll
    for (int t = 0; t < 8; t++)
#pragma unroll
      for (int reg = 0; reg < 4; reg++)
        XS[(w * 16 + quad * 4 + reg) * XSTR + t * 16 + n15] =
            f2bu(acc[t][reg]);
    __syncthreads();
    {
      const int row = tid >> 2;
      const int hd = tid & 3;
      const int cb = hd * 32;
      const int grow = row0 + row;
      float ps = 0.f, pd = 0.f;
      if (grow < N_) {
#pragma unroll
        for (int g = 0; g < 4; g++) {
          const uint4 v = *(const uint4*)&XS[row * XSTR + cb + g * 8];
          *(uint4*)&h[(size_t)grow * 128 + cb + g * 8] = v;
          const unsigned uu[4] = {v.x, v.y, v.z, v.w};
#pragma unroll
          for (int p = 0; p < 4; p++) {
            const float f0 = u2f(uu[p] << 16);
            const float f1 = u2f(uu[p] & 0xffff0000u);
            const int cc = cb + g * 8 + p * 2;
            ps = fmaf(f0, ats[cc], ps);     ps = fmaf(f1, ats[cc + 1], ps);
            pd = fmaf(f0, atd[cc], pd);     pd = fmaf(f1, atd[cc + 1], pd);
          }
        }
        a_src[grow * 4 + hd] = ps;
        a_dst[grow * 4 + hd] = pd;
      }
    }
  }
}

// ---------------------------------------------------------------------------
// Kernel 2: gather, 4 chains/node, one wave per node; lane owns 2 channels.
// (unchanged from round 8 — 145 µs, known-good)
// ---------------------------------------------------------------------------
__global__ __launch_bounds__(256) void k_gather4(
    const int* __restrict__ head4, const int2* __restrict__ nxt2,
    const float* __restrict__ a_src, const float* __restrict__ a_dst,
    const bf16* __restrict__ h, const float* __restrict__ bias,
    const float* __restrict__ gamma, const float* __restrict__ beta,
    float* __restrict__ out) {
  const int lane = threadIdx.x & 63;
  const int d = blockIdx.x * 4 + (threadIdx.x >> 6);
  if (d >= N_) return;
  const int head = lane >> 4;
  const int srcsel = lane & 48;  // head*16
  const float ad = a_dst[d * 4 + head];
  const int ch = lane * 2;

  int e = head4[d * 4 + (lane & 3)];  // my chain
  float acc0 = 0.f, acc1 = 0.f, sumw_mine = 0.f;

  while (__any(e != -1)) {
    const int c = (e < 0) ? 0 : e;
    const int2 sn = nxt2[c];                    // (src, next) — one 8B load
    const int s = sn.x;
    float ev = a_src[s * 4 + head] + ad;
    ev = (ev > 0.f) ? ev : 0.2f * ev;
    const float w = (e < 0) ? 0.f : __expf(ev);
    sumw_mine += w;
    const int soff = s << 7;

#pragma unroll
    for (int j = 0; j < 4; j++) {
      const float wj = __shfl(w, srcsel | j);
      const int oj = __shfl(soff, j);
      const __hip_bfloat162 hv = *(const __hip_bfloat162*)&h[oj + ch];
      acc0 = fmaf(wj, __low2float(hv), acc0);
      acc1 = fmaf(wj, __high2float(hv), acc1);
    }
    e = (e < 0) ? -1 : sn.y;
  }

  float sumw = sumw_mine;
  sumw += __shfl_xor(sumw, 1);
  sumw += __shfl_xor(sumw, 2);

  const float inv = 1.0f / (sumw + 1e-16f);
  const float2 bi = *(const float2*)&bias[ch];
  const float v0 = acc0 * inv + bi.x;
  const float v1 = acc1 * inv + bi.y;
  // cos^2+sin^2 == 1 to 1 ulp -> mag = sqrt(v^2 + 1e-12)
  const float m0i = sqrtf(v0 * v0 + 1e-12f);
  const float m1i = sqrtf(v1 * v1 + 1e-12f);

  float s1 = m0i + m1i;
#pragma unroll
  for (int off = 32; off > 0; off >>= 1) s1 += __shfl_xor(s1, off);
  const float mu = s1 * (1.0f / 128.0f);
  const float d0 = m0i - mu, d1 = m1i - mu;
  float q = d0 * d0 + d1 * d1;
#pragma unroll
  for (int off = 32; off > 0; off >>= 1) q += __shfl_xor(q, off);
  const float rstd = rsqrtf(q * (1.0f / 128.0f) + 1e-5f);
  const float2 ga = *(const float2*)&gamma[ch];
  const float2 be = *(const float2*)&beta[ch];
  const float hn0 = d0 * rstd * ga.x + be.x;
  const float hn1 = d1 * rstd * ga.y + be.y;
  const float g0 = 0.5f * hn0 * (1.0f + erff(hn0 * 0.70710678118654752f));
  const float g1 = 0.5f * hn1 * (1.0f + erff(hn1 * 0.70710678118654752f));
  *(float2*)&out[(size_t)d * 128 + ch] = make_float2(g0, g1);
}

// ---------------------------------------------------------------------------
extern "C" void kernel_launch(void* const* d_in, const int* in_sizes, int n_in,
                              void* d_out, int out_size, void* d_ws, size_t ws_size,
                              hipStream_t stream) {
  const float* x       = (const float*)d_in[0];
  const int*   ei      = (const int*)d_in[1];
  const float* W       = (const float*)d_in[2];
  const float* att_src = (const float*)d_in[3];
  const float* att_dst = (const float*)d_in[4];
  const float* bias    = (const float*)d_in[5];
  const float* gamma   = (const float*)d_in[7];
  const float* beta    = (const float*)d_in[8];
  float* out = (float*)d_out;

  // workspace (43.2 MB)
  bf16*  h     = (bf16*)d_ws;                        // N*128 bf16 (25.6 MB)
  float* a_src = (float*)(h + (size_t)N_ * D_);      // N*4 f32 (1.6 MB)
  float* a_dst = a_src + (size_t)N_ * H_;            // N*4 f32 (1.6 MB)
  int*   head4 = (int*)(a_dst + (size_t)N_ * H_);    // N*4 int (1.6 MB)
  int2*  nxt2  = (int2*)(head4 + (size_t)N_ * 4);    // E int2 (12.8 MB)

  hipMemsetAsync(head4, 0xFF, (size_t)N_ * 4 * sizeof(int), stream);

  k_linear_link<<<768, 256, 0, stream>>>(x, W, att_src, att_dst, ei, head4,
                                         nxt2, h, a_src, a_dst);
  k_gather4<<<(N_ + 3) / 4, 256, 0, stream>>>(head4, nxt2, a_src, a_dst, h,
                                              bias, gamma, beta, out);
}